// Round 11
// baseline (717.504 us; speedup 1.0000x reference)
//
#include <hip/hip_runtime.h>

#define NAT 20000
#define NE  640000
#define NT  2000000
#define CH  128
#define EF  64
#define NB  4096
#define PI_F 3.14159265358979f
#define NLOG2E (-1.44269504088896f)

#define G_GEMM 625
#define G_LUT  2049
#define G_HIST 1024

typedef __attribute__((ext_vector_type(8))) __bf16 bf16x8;
typedef __attribute__((ext_vector_type(4))) float floatx4;
typedef __attribute__((ext_vector_type(2))) float floatx2;

__device__ __forceinline__ float fsigmoid(float x) {
    return __builtin_amdgcn_rcpf(1.0f + __expf(-x));
}
__device__ __forceinline__ float fsilu(float x) { return x * fsigmoid(x); }

__device__ __forceinline__ floatx2 fsigmoid2(floatx2 x) {
    floatx2 nx = x * NLOG2E;
    floatx2 e = {__builtin_amdgcn_exp2f(nx.x), __builtin_amdgcn_exp2f(nx.y)};
    floatx2 d = e + 1.0f;
    return floatx2{__builtin_amdgcn_rcpf(d.x), __builtin_amdgcn_rcpf(d.y)};
}
__device__ __forceinline__ floatx2 fsilu2(floatx2 x) { return x * fsigmoid2(x); }

// ---------------- standalone gemm (final W_post pass; in-place safe) ----------------
__global__ __launch_bounds__(256) void gemm128(const float* __restrict__ X,
                                               const float* __restrict__ W,
                                               float* __restrict__ Y) {
    __shared__ float Xs[32 * 128];
    __shared__ float Ws[32 * 128];
    int tid = threadIdx.x;
    int row0 = blockIdx.x * 32;

    const float4* Xg = (const float4*)(X + (size_t)row0 * 128);
    float4* Xs4 = (float4*)Xs;
#pragma unroll
    for (int i = 0; i < 4; ++i) Xs4[tid + 256 * i] = Xg[tid + 256 * i];

    int r0 = (tid >> 5) << 2;
    int c0 = (tid & 31) << 2;
    floatx4 acc[4];
#pragma unroll
    for (int i = 0; i < 4; ++i) acc[i] = floatx4{0.f, 0.f, 0.f, 0.f};

    for (int kb = 0; kb < 4; ++kb) {
        __syncthreads();
        const float4* Wg = (const float4*)(W + kb * 32 * 128);
        float4* Ws4 = (float4*)Ws;
#pragma unroll
        for (int i = 0; i < 4; ++i) Ws4[tid + 256 * i] = Wg[tid + 256 * i];
        __syncthreads();
#pragma unroll
        for (int kk = 0; kk < 32; ++kk) {
            int k = kb * 32 + kk;
            floatx4 wv = *(const floatx4*)&Ws[kk * 128 + c0];
            float x0 = Xs[(r0 + 0) * 128 + k];
            float x1 = Xs[(r0 + 1) * 128 + k];
            float x2 = Xs[(r0 + 2) * 128 + k];
            float x3 = Xs[(r0 + 3) * 128 + k];
            acc[0] += x0 * wv;
            acc[1] += x1 * wv;
            acc[2] += x2 * wv;
            acc[3] += x3 * wv;
        }
    }
#pragma unroll
    for (int i = 0; i < 4; ++i)
        *(floatx4*)&Y[(size_t)(row0 + r0 + i) * 128 + c0] = acc[i];
}

// ---------------- R11 prep mega-kernel: gemm-h | build_lut | hist (independent) ---------
__global__ __launch_bounds__(256) void prep_k(const float* __restrict__ X,
                                              const float* __restrict__ W,
                                              float* __restrict__ Y,
                                              const float* __restrict__ W1,
                                              const float* __restrict__ W2,
                                              const float* __restrict__ G1,
                                              const float* __restrict__ G2,
                                              float* __restrict__ lut,
                                              const int* __restrict__ tri,
                                              const int* __restrict__ nl,
                                              int* __restrict__ tcnt,
                                              int* __restrict__ ecnt) {
    __shared__ float Xs[32 * 128];      // gemm path (32 KB, also overlays lut arrays)
    __shared__ float Ws[32 * 128];
    int bid = blockIdx.x, tid = threadIdx.x;

    if (bid < G_GEMM) {
        // ---- gemm-h: Y[bid*32 .. +32) = X @ W ----
        int row0 = bid * 32;
        const float4* Xg = (const float4*)(X + (size_t)row0 * 128);
        float4* Xs4 = (float4*)Xs;
#pragma unroll
        for (int i = 0; i < 4; ++i) Xs4[tid + 256 * i] = Xg[tid + 256 * i];
        int r0 = (tid >> 5) << 2;
        int c0 = (tid & 31) << 2;
        floatx4 acc[4];
#pragma unroll
        for (int i = 0; i < 4; ++i) acc[i] = floatx4{0.f, 0.f, 0.f, 0.f};
        for (int kb = 0; kb < 4; ++kb) {
            __syncthreads();
            const float4* Wg = (const float4*)(W + kb * 32 * 128);
            float4* Ws4 = (float4*)Ws;
#pragma unroll
            for (int i = 0; i < 4; ++i) Ws4[tid + 256 * i] = Wg[tid + 256 * i];
            __syncthreads();
#pragma unroll
            for (int kk = 0; kk < 32; ++kk) {
                int k = kb * 32 + kk;
                floatx4 wv = *(const floatx4*)&Ws[kk * 128 + c0];
                float x0 = Xs[(r0 + 0) * 128 + k];
                float x1 = Xs[(r0 + 1) * 128 + k];
                float x2 = Xs[(r0 + 2) * 128 + k];
                float x3 = Xs[(r0 + 3) * 128 + k];
                acc[0] += x0 * wv;
                acc[1] += x1 * wv;
                acc[2] += x2 * wv;
                acc[3] += x3 * wv;
            }
        }
#pragma unroll
        for (int i = 0; i < 4; ++i)
            *(floatx4*)&Y[(size_t)(row0 + r0 + i) * 128 + c0] = acc[i];
    } else if (bid < G_GEMM + G_LUT) {
        // ---- build_lut: 2 bins per block (tid>>7 selects bin) ----
        float* rb = Xs;              // [2][64] overlay
        float* hm = Xs + 128;        // [2][64]
        float* hg = Xs + 256;        // [2][64]
        int half = tid >> 7, t = tid & 127;
        int p = (bid - G_GEMM) * 2 + half;
        bool live = (p <= NB);
        float d = p * (5.0f / NB);
        if (live && t < 64) {
            float ctr = t * (5.0f / 63.0f);
            float sig = 5.0f / 64.0f;
            float z = (d - ctr);
            float g = __expf(-z * z / (2.0f * sig * sig));
            float env = (d < 5.0f) ? 0.5f * (1.0f + __cosf(PI_F * d / 5.0f)) : 0.0f;
            rb[half * 64 + t] = g * env;
        }
        __syncthreads();
        if (live) {
            int j = t & 63;
            const float* Wm = (t < 64) ? W1 : G1;
            float s = 0.0f;
            for (int k = 0; k < 64; ++k) s += rb[half * 64 + k] * Wm[k * 64 + j];
            float hv = fsilu(s);
            if (t < 64) hm[half * 64 + j] = hv; else hg[half * 64 + j] = hv;
        }
        __syncthreads();
        if (live) {
            float m = 0.0f, g = 0.0f;
            for (int j = 0; j < 64; ++j) {
                m += hm[half * 64 + j] * W2[j * 128 + t];
                g += hg[half * 64 + j] * G2[j * 128 + t];
            }
            lut[(size_t)p * 128 + t] = m * fsigmoid(g);
        }
    } else {
        // ---- hist ----
        int g0 = (bid - G_GEMM - G_LUT) * 256 + tid;
        int stride = G_HIST * 256;
        for (int g = g0; g < NT + NE; g += stride) {
            if (g < NT) atomicAdd(&tcnt[tri[(size_t)g * 3 + 1]], 1);
            else        atomicAdd(&ecnt[nl[g - NT]], 1);
        }
    }
}

// ---------------- scan ----------------
__global__ __launch_bounds__(1024) void scan20k(int* __restrict__ tcnt, int* __restrict__ toff, int* __restrict__ tcur,
                                                int* __restrict__ ecnt, int* __restrict__ eoff, int* __restrict__ ecur) {
    int* cnt; int* off; int* cur;
    if (blockIdx.x == 0) { cnt = tcnt; off = toff; cur = tcur; }
    else                 { cnt = ecnt; off = eoff; cur = ecur; }
    __shared__ int part[1024];
    int t = threadIdx.x;
    const int PER = 20;
    int vals[PER]; int lsum = 0;
#pragma unroll
    for (int i = 0; i < PER; ++i) {
        int idx = t * PER + i;
        int v = (idx < NAT) ? cnt[idx] : 0;
        vals[i] = v; lsum += v;
    }
    part[t] = lsum;
    __syncthreads();
    for (int d = 1; d < 1024; d <<= 1) {
        int add = (t >= d) ? part[t - d] : 0;
        __syncthreads();
        part[t] += add;
        __syncthreads();
    }
    int run = part[t] - lsum;
#pragma unroll
    for (int i = 0; i < PER; ++i) {
        int idx = t * PER + i;
        if (idx < NAT) { off[idx] = run; cur[idx] = run; run += vals[i]; }
    }
    if (t == 1023) off[NAT] = part[1023];
}

// ---------------- scatter payloads ----------------
__global__ __launch_bounds__(256) void scatter_k(const int* __restrict__ tri,
                                                 const int* __restrict__ nl,
                                                 const float* __restrict__ rij,
                                                 const float* __restrict__ rik,
                                                 const float* __restrict__ ang,
                                                 const float* __restrict__ dist,
                                                 int* __restrict__ tcur, int* __restrict__ ecur,
                                                 float* __restrict__ tdata,
                                                 float2* __restrict__ edata) {
    int stride = gridDim.x * 256;
    for (int g = blockIdx.x * 256 + threadIdx.x; g < NT + NE; g += stride) {
        if (g < NT) {
            int p = atomicAdd(&tcur[tri[(size_t)g * 3 + 1]], 1);
            float* dst = tdata + (size_t)p * 3;
            dst[0] = rij[g];
            dst[1] = rik[g];
            dst[2] = __cosf(ang[g]);
        } else {
            int e = g - NT;
            int p = atomicAdd(&ecur[nl[e]], 1);
            edata[p] = make_float2(dist[e], __int_as_float(nl[NE + e]));
        }
    }
}

// ---------------- fused three-body + two-body + owner inject ----------------
// acc must be pre-zeroed; all acc updates are atomic adds.
__global__ __launch_bounds__(256) void fused_bodies(const float* __restrict__ tdata,
                                                    const int* __restrict__ toff,
                                                    const float2* __restrict__ edata,
                                                    const int* __restrict__ eoff,
                                                    const float* __restrict__ h,
                                                    const float* __restrict__ lut,
                                                    const int* __restrict__ nl,
                                                    const float* __restrict__ thW1,
                                                    const float* __restrict__ thW2,
                                                    const float* __restrict__ thG1,
                                                    const float* __restrict__ thG2,
                                                    float* __restrict__ W3,
                                                    float* __restrict__ acc) {
    __shared__ __bf16 lw2[64 * 128];
    __shared__ __bf16 lg2[64 * 128];
    __shared__ float lw1[192];
    __shared__ float lg1[192];
    int tid = threadIdx.x;
    for (int i = tid; i < 192; i += 256) { lw1[i] = thW1[i]; lg1[i] = thG1[i]; }
    // B-fragment swizzle (validated R1/R2): (k,c) -> (((tile*2+s)*64)+q*16+n)*8+j
    for (int e = tid; e < 64 * 128; e += 256) {
        int k = e >> 7, c = e & 127;
        int tile = c >> 4, n = c & 15, s = k >> 5, q = (k >> 3) & 3, j = k & 7;
        int li = ((((tile << 1) + s) * 64) + (q << 4) + n) * 8 + j;
        lw2[li] = (__bf16)thW2[e];
        lg2[li] = (__bf16)thG2[e];
    }
    __syncthreads();

    int lane = tid & 63;
    int q = lane >> 4, n = lane & 15;
    int lfrag = ((q << 4) + n) << 3;
    int c2 = lane << 1;
    int wid = (blockIdx.x << 2) + (tid >> 6);
    int nw = gridDim.x << 2;

    for (int a = wid; a < NAT; a += nw) {
        // ---------- threebody atom ----------
        {
            int base = toff[a];
            int cnt = toff[a + 1] - base;
            floatx2 accT[8];
#pragma unroll
            for (int t = 0; t < 8; ++t) accT[t] = floatx2{0.f, 0.f};

            for (int i0 = 0; i0 < cnt; i0 += 64) {
                int rem = cnt - i0;
                float tx = 0.f, ty = 0.f, tz = 0.f;
                if (lane < rem) {
                    const float* p = tdata + (size_t)(base + i0 + lane) * 3;
                    tx = p[0]; ty = p[1]; tz = p[2];
                }
                float rrv[4], kkv[4], ccv[4];
#pragma unroll
                for (int ms = 0; ms < 4; ++ms) {
                    rrv[ms] = __shfl(tx, (ms << 4) + n);
                    kkv[ms] = __shfl(ty, (ms << 4) + n);
                    ccv[ms] = __shfl(tz, (ms << 4) + n);
                }
                int nms = rem >= 64 ? 4 : ((rem + 15) >> 4);

                bf16x8 fam[4][2], fag[4][2];
#pragma unroll
                for (int s = 0; s < 2; ++s) {
                    int kb = s * 32 + (q << 3);
#pragma unroll
                    for (int j2 = 0; j2 < 4; ++j2) {
                        floatx2 wa0 = *(const floatx2*)&lw1[kb + 2 * j2];
                        floatx2 wa1 = *(const floatx2*)&lw1[64 + kb + 2 * j2];
                        floatx2 wa2 = *(const floatx2*)&lw1[128 + kb + 2 * j2];
                        floatx2 wb0 = *(const floatx2*)&lg1[kb + 2 * j2];
                        floatx2 wb1 = *(const floatx2*)&lg1[64 + kb + 2 * j2];
                        floatx2 wb2 = *(const floatx2*)&lg1[128 + kb + 2 * j2];
#pragma unroll
                        for (int ms = 0; ms < 4; ++ms) {
                            if (ms >= nms) break;
                            floatx2 rr2 = {rrv[ms], rrv[ms]};
                            floatx2 kk2 = {kkv[ms], kkv[ms]};
                            floatx2 cc2 = {ccv[ms], ccv[ms]};
                            floatx2 um = rr2 * wa0 + kk2 * wa1 + cc2 * wa2;
                            floatx2 ug = rr2 * wb0 + kk2 * wb1 + cc2 * wb2;
                            floatx2 sm = fsilu2(um);
                            floatx2 sg = fsilu2(ug);
                            fam[ms][s][2 * j2]     = (__bf16)sm.x;
                            fam[ms][s][2 * j2 + 1] = (__bf16)sm.y;
                            fag[ms][s][2 * j2]     = (__bf16)sg.x;
                            fag[ms][s][2 * j2 + 1] = (__bf16)sg.y;
                        }
                    }
                }

#pragma unroll
                for (int tile = 0; tile < 8; ++tile) {
                    __builtin_amdgcn_sched_barrier(0);
                    const __bf16* pw = lw2 + lfrag + tile * 1024;
                    const __bf16* pg = lg2 + lfrag + tile * 1024;
                    bf16x8 bw0 = *(const bf16x8*)(pw);
                    bf16x8 bw1 = *(const bf16x8*)(pw + 512);
                    bf16x8 bg0 = *(const bf16x8*)(pg);
                    bf16x8 bg1 = *(const bf16x8*)(pg + 512);
#pragma unroll
                    for (int ms = 0; ms < 4; ++ms) {
                        if (ms >= nms) break;
                        floatx4 am = {0.f, 0.f, 0.f, 0.f};
                        floatx4 ag = {0.f, 0.f, 0.f, 0.f};
                        am = __builtin_amdgcn_mfma_f32_16x16x32_bf16(fam[ms][0], bw0, am, 0, 0, 0);
                        am = __builtin_amdgcn_mfma_f32_16x16x32_bf16(fam[ms][1], bw1, am, 0, 0, 0);
                        ag = __builtin_amdgcn_mfma_f32_16x16x32_bf16(fag[ms][0], bg0, ag, 0, 0, 0);
                        ag = __builtin_amdgcn_mfma_f32_16x16x32_bf16(fag[ms][1], bg1, ag, 0, 0, 0);
                        floatx2 s01 = fsigmoid2(floatx2{ag[0], ag[1]});
                        floatx2 s23 = fsigmoid2(floatx2{ag[2], ag[3]});
                        accT[tile] += floatx2{am[0], am[1]} * s01
                                    + floatx2{am[2], am[3]} * s23;
                    }
                }
            }
            // reduce + W3 store + OWNER INJECT: acc[nl0[a]] += h[a] * W3[a]
            int dst = nl[a];   // neighbour_list row 0, index a (a < NAT <= NE)
#pragma unroll
            for (int tile = 0; tile < 8; ++tile) {
                float v = accT[tile].x + accT[tile].y;
                v += __shfl_xor(v, 16);
                v += __shfl_xor(v, 32);
                if (q == 0) {
                    int c = (tile << 4) + n;
                    W3[(size_t)a * 128 + c] = v;
                    float hv = h[(size_t)a * 128 + c];
                    unsafeAtomicAdd(&acc[(size_t)dst * 128 + c], hv * v);
                }
            }
        }
        // ---------- twobody atom (latency-bound; rides threebody stalls) ----------
        {
            int base = eoff[a];
            int cnt = eoff[a + 1] - base;
            float s0 = 0.f, s1 = 0.f, t0 = 0.f, t1 = 0.f;
            for (int i0 = 0; i0 < cnt; i0 += 64) {
                int rem = cnt - i0; if (rem > 64) rem = 64;
                float2 el = make_float2(0.f, 0.f);
                if (lane < rem) el = edata[base + i0 + lane];
                int j = 0;
                for (; j + 2 <= rem; j += 2) {
                    float dA = __shfl(el.x, j);
                    int aA = __float_as_int(__shfl(el.y, j));
                    float dB = __shfl(el.x, j + 1);
                    int aB = __float_as_int(__shfl(el.y, j + 1));
                    float xA = dA * ((float)NB / 5.0f);
                    int iA = (int)xA; if (iA > NB - 1) iA = NB - 1;
                    float fA = xA - (float)iA;
                    float xB = dB * ((float)NB / 5.0f);
                    int iB = (int)xB; if (iB > NB - 1) iB = NB - 1;
                    float fB = xB - (float)iB;
                    float2 l0A = *(const float2*)&lut[(size_t)iA * 128 + c2];
                    float2 l1A = *(const float2*)&lut[(size_t)(iA + 1) * 128 + c2];
                    float2 hvA = *(const float2*)&h[(size_t)aA * 128 + c2];
                    float2 l0B = *(const float2*)&lut[(size_t)iB * 128 + c2];
                    float2 l1B = *(const float2*)&lut[(size_t)(iB + 1) * 128 + c2];
                    float2 hvB = *(const float2*)&h[(size_t)aB * 128 + c2];
                    s0 += hvA.x * (l0A.x + (l1A.x - l0A.x) * fA);
                    s1 += hvA.y * (l0A.y + (l1A.y - l0A.y) * fA);
                    t0 += hvB.x * (l0B.x + (l1B.x - l0B.x) * fB);
                    t1 += hvB.y * (l0B.y + (l1B.y - l0B.y) * fB);
                }
                if (j < rem) {
                    float d = __shfl(el.x, j);
                    int a1 = __float_as_int(__shfl(el.y, j));
                    float x = d * ((float)NB / 5.0f);
                    int i = (int)x; if (i > NB - 1) i = NB - 1;
                    float f = x - (float)i;
                    float2 l0 = *(const float2*)&lut[(size_t)i * 128 + c2];
                    float2 l1 = *(const float2*)&lut[(size_t)(i + 1) * 128 + c2];
                    float2 hv = *(const float2*)&h[(size_t)a1 * 128 + c2];
                    s0 += hv.x * (l0.x + (l1.x - l0.x) * f);
                    s1 += hv.y * (l0.y + (l1.y - l0.y) * f);
                }
            }
            unsafeAtomicAdd(&acc[(size_t)a * 128 + c2], s0 + t0);
            unsafeAtomicAdd(&acc[(size_t)a * 128 + c2 + 1], s1 + t1);
        }
    }
}

extern "C" void kernel_launch(void* const* d_in, const int* in_sizes, int n_in,
                              void* d_out, int out_size, void* d_ws, size_t ws_size,
                              hipStream_t stream) {
    const float* features = (const float*)d_in[0];
    const float* dist = (const float*)d_in[1];
    const float* ang = (const float*)d_in[2];
    const float* rij = (const float*)d_in[3];
    const float* rik = (const float*)d_in[4];
    const int* nl = (const int*)d_in[5];
    const int* tri = (const int*)d_in[6];
    const float* W_pre = (const float*)d_in[7];
    const float* tbW1 = (const float*)d_in[8];
    const float* tbW2 = (const float*)d_in[9];
    const float* tbG1 = (const float*)d_in[10];
    const float* tbG2 = (const float*)d_in[11];
    const float* thW1 = (const float*)d_in[12];
    const float* thW2 = (const float*)d_in[13];
    const float* thG1 = (const float*)d_in[14];
    const float* thG2 = (const float*)d_in[15];
    const float* W_post = (const float*)d_in[16];
    float* out = (float*)d_out;

    // workspace layout (~52 MB); acc aliases d_out
    float* tdata = (float*)d_ws;                         // NT * 12B = 24 MB
    float2* edata = (float2*)(tdata + (size_t)NT * 3);   // NE * 8B = 5.1 MB
    float* h   = (float*)(edata + NE);                   // 10.24 MB
    float* W3  = h + (size_t)NAT * CH;                   // 10.24 MB
    float* lut = W3 + (size_t)NAT * CH;                  // 2.1 MB
    int* tcnt = (int*)(lut + (size_t)(NB + 1) * CH);
    int* ecnt = tcnt + NAT;
    int* toff = ecnt + NAT;                              // NAT+1
    int* eoff = toff + NAT + 1;                          // NAT+1
    int* tcur = eoff + NAT + 1;
    int* ecur = tcur + NAT;
    float* acc = out;

    hipMemsetAsync(tcnt, 0, (size_t)2 * NAT * sizeof(int), stream);
    hipMemsetAsync(acc, 0, (size_t)NAT * CH * sizeof(float), stream);  // atomic target

    prep_k<<<G_GEMM + G_LUT + G_HIST, 256, 0, stream>>>(
        features, W_pre, h, tbW1, tbW2, tbG1, tbG2, lut, tri, nl, tcnt, ecnt);
    scan20k<<<2, 1024, 0, stream>>>(tcnt, toff, tcur, ecnt, eoff, ecur);
    scatter_k<<<1024, 256, 0, stream>>>(tri, nl, rij, rik, ang, dist,
                                        tcur, ecur, tdata, edata);
    fused_bodies<<<1024, 256, 0, stream>>>(tdata, toff, edata, eoff, h, lut, nl,
                                           thW1, thW2, thG1, thG2, W3, acc);
    gemm128<<<NAT / 32, 256, 0, stream>>>(acc, W_post, out);
}

// Round 12
// 691.689 us; speedup vs baseline: 1.0373x; 1.0373x over previous
//
#include <hip/hip_runtime.h>
#include <hip/hip_fp16.h>

#define NAT 20000
#define NE  640000
#define NT  2000000
#define CH  128
#define EF  64
#define NB  4096
#define PI_F 3.14159265358979f
#define NLOG2E (-1.44269504088896f)

#define G_SC   1024
#define G_GEMM 625
#define G_LUT  2049

typedef __attribute__((ext_vector_type(8))) __bf16 bf16x8;
typedef __attribute__((ext_vector_type(4))) float floatx4;
typedef __attribute__((ext_vector_type(2))) float floatx2;

__device__ __forceinline__ float fsigmoid(float x) {
    return __builtin_amdgcn_rcpf(1.0f + __expf(-x));
}
__device__ __forceinline__ float fsilu(float x) { return x * fsigmoid(x); }

__device__ __forceinline__ floatx2 fsigmoid2(floatx2 x) {
    floatx2 nx = x * NLOG2E;
    floatx2 e = {__builtin_amdgcn_exp2f(nx.x), __builtin_amdgcn_exp2f(nx.y)};
    floatx2 d = e + 1.0f;
    return floatx2{__builtin_amdgcn_rcpf(d.x), __builtin_amdgcn_rcpf(d.y)};
}
__device__ __forceinline__ floatx2 fsilu2(floatx2 x) { return x * fsigmoid2(x); }

// ---------------- standalone gemm (final W_post pass; in-place safe) ----------------
__global__ __launch_bounds__(256) void gemm128(const float* __restrict__ X,
                                               const float* __restrict__ W,
                                               float* __restrict__ Y) {
    __shared__ float Xs[32 * 128];
    __shared__ float Ws[32 * 128];
    int tid = threadIdx.x;
    int row0 = blockIdx.x * 32;

    const float4* Xg = (const float4*)(X + (size_t)row0 * 128);
    float4* Xs4 = (float4*)Xs;
#pragma unroll
    for (int i = 0; i < 4; ++i) Xs4[tid + 256 * i] = Xg[tid + 256 * i];

    int r0 = (tid >> 5) << 2;
    int c0 = (tid & 31) << 2;
    floatx4 acc[4];
#pragma unroll
    for (int i = 0; i < 4; ++i) acc[i] = floatx4{0.f, 0.f, 0.f, 0.f};

    for (int kb = 0; kb < 4; ++kb) {
        __syncthreads();
        const float4* Wg = (const float4*)(W + kb * 32 * 128);
        float4* Ws4 = (float4*)Ws;
#pragma unroll
        for (int i = 0; i < 4; ++i) Ws4[tid + 256 * i] = Wg[tid + 256 * i];
        __syncthreads();
#pragma unroll
        for (int kk = 0; kk < 32; ++kk) {
            int k = kb * 32 + kk;
            floatx4 wv = *(const floatx4*)&Ws[kk * 128 + c0];
            float x0 = Xs[(r0 + 0) * 128 + k];
            float x1 = Xs[(r0 + 1) * 128 + k];
            float x2 = Xs[(r0 + 2) * 128 + k];
            float x3 = Xs[(r0 + 3) * 128 + k];
            acc[0] += x0 * wv;
            acc[1] += x1 * wv;
            acc[2] += x2 * wv;
            acc[3] += x3 * wv;
        }
    }
#pragma unroll
    for (int i = 0; i < 4; ++i)
        *(floatx4*)&Y[(size_t)(row0 + r0 + i) * 128 + c0] = acc[i];
}

// ---------------- hist (must precede scan) ----------------
__global__ __launch_bounds__(256) void hist_k(const int* __restrict__ tri,
                                              const int* __restrict__ nl,
                                              int* __restrict__ tcnt,
                                              int* __restrict__ ecnt) {
    int stride = gridDim.x * 256;
    for (int g = blockIdx.x * 256 + threadIdx.x; g < NT + NE; g += stride) {
        if (g < NT) atomicAdd(&tcnt[tri[(size_t)g * 3 + 1]], 1);
        else        atomicAdd(&ecnt[nl[g - NT]], 1);
    }
}

// ---------------- scan ----------------
__global__ __launch_bounds__(1024) void scan20k(int* __restrict__ tcnt, int* __restrict__ toff, int* __restrict__ tcur,
                                                int* __restrict__ ecnt, int* __restrict__ eoff, int* __restrict__ ecur) {
    int* cnt; int* off; int* cur;
    if (blockIdx.x == 0) { cnt = tcnt; off = toff; cur = tcur; }
    else                 { cnt = ecnt; off = eoff; cur = ecur; }
    __shared__ int part[1024];
    int t = threadIdx.x;
    const int PER = 20;
    int vals[PER]; int lsum = 0;
#pragma unroll
    for (int i = 0; i < PER; ++i) {
        int idx = t * PER + i;
        int v = (idx < NAT) ? cnt[idx] : 0;
        vals[i] = v; lsum += v;
    }
    part[t] = lsum;
    __syncthreads();
    for (int d = 1; d < 1024; d <<= 1) {
        int add = (t >= d) ? part[t - d] : 0;
        __syncthreads();
        part[t] += add;
        __syncthreads();
    }
    int run = part[t] - lsum;
#pragma unroll
    for (int i = 0; i < PER; ++i) {
        int idx = t * PER + i;
        if (idx < NAT) { off[idx] = run; cur[idx] = run; run += vals[i]; }
    }
    if (t == 1023) off[NAT] = part[1023];
}

// ---------------- R12 mid mega-kernel: scatter | gemm-h | build_lut ----------------
// Scatter (the long pole, ~2.64M atomic-bucketed writes) gets blocks [0,G_SC);
// gemm-h and build_lut hide under it instead of serializing after.
// tdata payload 8B: .x = half2(rij, rik), .y = cos(angle)  (fp16 rel-err 5e-4 << 2% budget)
__global__ __launch_bounds__(256) void mid_k(const int* __restrict__ tri,
                                             const int* __restrict__ nl,
                                             const float* __restrict__ rij,
                                             const float* __restrict__ rik,
                                             const float* __restrict__ ang,
                                             const float* __restrict__ dist,
                                             int* __restrict__ tcur, int* __restrict__ ecur,
                                             float2* __restrict__ tdata,
                                             float2* __restrict__ edata,
                                             const float* __restrict__ X,
                                             const float* __restrict__ W,
                                             float* __restrict__ Y,
                                             const float* __restrict__ W1,
                                             const float* __restrict__ W2,
                                             const float* __restrict__ G1,
                                             const float* __restrict__ G2,
                                             float* __restrict__ lut) {
    __shared__ float Xs[32 * 128];
    __shared__ float Ws[32 * 128];
    int bid = blockIdx.x, tid = threadIdx.x;

    if (bid < G_SC) {
        // ---- scatter ----
        int stride = G_SC * 256;
        for (int g = bid * 256 + tid; g < NT + NE; g += stride) {
            if (g < NT) {
                int p = atomicAdd(&tcur[tri[(size_t)g * 3 + 1]], 1);
                unsigned lo = __half_as_ushort(__float2half_rn(rij[g]));
                unsigned hi = __half_as_ushort(__float2half_rn(rik[g]));
                tdata[p] = make_float2(__uint_as_float(lo | (hi << 16)), __cosf(ang[g]));
            } else {
                int e = g - NT;
                int p = atomicAdd(&ecur[nl[e]], 1);
                edata[p] = make_float2(dist[e], __int_as_float(nl[NE + e]));
            }
        }
    } else if (bid < G_SC + G_GEMM) {
        // ---- gemm-h ----
        int row0 = (bid - G_SC) * 32;
        const float4* Xg = (const float4*)(X + (size_t)row0 * 128);
        float4* Xs4 = (float4*)Xs;
#pragma unroll
        for (int i = 0; i < 4; ++i) Xs4[tid + 256 * i] = Xg[tid + 256 * i];
        int r0 = (tid >> 5) << 2;
        int c0 = (tid & 31) << 2;
        floatx4 acc[4];
#pragma unroll
        for (int i = 0; i < 4; ++i) acc[i] = floatx4{0.f, 0.f, 0.f, 0.f};
        for (int kb = 0; kb < 4; ++kb) {
            __syncthreads();
            const float4* Wg = (const float4*)(W + kb * 32 * 128);
            float4* Ws4 = (float4*)Ws;
#pragma unroll
            for (int i = 0; i < 4; ++i) Ws4[tid + 256 * i] = Wg[tid + 256 * i];
            __syncthreads();
#pragma unroll
            for (int kk = 0; kk < 32; ++kk) {
                int k = kb * 32 + kk;
                floatx4 wv = *(const floatx4*)&Ws[kk * 128 + c0];
                float x0 = Xs[(r0 + 0) * 128 + k];
                float x1 = Xs[(r0 + 1) * 128 + k];
                float x2 = Xs[(r0 + 2) * 128 + k];
                float x3 = Xs[(r0 + 3) * 128 + k];
                acc[0] += x0 * wv;
                acc[1] += x1 * wv;
                acc[2] += x2 * wv;
                acc[3] += x3 * wv;
            }
        }
#pragma unroll
        for (int i = 0; i < 4; ++i)
            *(floatx4*)&Y[(size_t)(row0 + r0 + i) * 128 + c0] = acc[i];
    } else {
        // ---- build_lut: 2 bins per block ----
        float* rb = Xs;
        float* hm = Xs + 128;
        float* hg = Xs + 256;
        int half = tid >> 7, t = tid & 127;
        int p = (bid - G_SC - G_GEMM) * 2 + half;
        bool live = (p <= NB);
        float d = p * (5.0f / NB);
        if (live && t < 64) {
            float ctr = t * (5.0f / 63.0f);
            float sig = 5.0f / 64.0f;
            float z = (d - ctr);
            float g = __expf(-z * z / (2.0f * sig * sig));
            float env = (d < 5.0f) ? 0.5f * (1.0f + __cosf(PI_F * d / 5.0f)) : 0.0f;
            rb[half * 64 + t] = g * env;
        }
        __syncthreads();
        if (live) {
            int j = t & 63;
            const float* Wm = (t < 64) ? W1 : G1;
            float s = 0.0f;
            for (int k = 0; k < 64; ++k) s += rb[half * 64 + k] * Wm[k * 64 + j];
            float hv = fsilu(s);
            if (t < 64) hm[half * 64 + j] = hv; else hg[half * 64 + j] = hv;
        }
        __syncthreads();
        if (live) {
            float m = 0.0f, g = 0.0f;
            for (int j = 0; j < 64; ++j) {
                m += hm[half * 64 + j] * W2[j * 128 + t];
                g += hg[half * 64 + j] * G2[j * 128 + t];
            }
            lut[(size_t)p * 128 + t] = m * fsigmoid(g);
        }
    }
}

// ---------------- fused three-body + two-body (R10 form: plain acc stores) ----------------
__global__ __launch_bounds__(256) void fused_bodies(const float2* __restrict__ tdata,
                                                    const int* __restrict__ toff,
                                                    const float2* __restrict__ edata,
                                                    const int* __restrict__ eoff,
                                                    const float* __restrict__ h,
                                                    const float* __restrict__ lut,
                                                    const float* __restrict__ thW1,
                                                    const float* __restrict__ thW2,
                                                    const float* __restrict__ thG1,
                                                    const float* __restrict__ thG2,
                                                    float* __restrict__ W3,
                                                    float* __restrict__ acc) {
    __shared__ __bf16 lw2[64 * 128];
    __shared__ __bf16 lg2[64 * 128];
    __shared__ float lw1[192];
    __shared__ float lg1[192];
    int tid = threadIdx.x;
    for (int i = tid; i < 192; i += 256) { lw1[i] = thW1[i]; lg1[i] = thG1[i]; }
    // B-fragment swizzle (validated R1/R2): (k,c) -> (((tile*2+s)*64)+q*16+n)*8+j
    for (int e = tid; e < 64 * 128; e += 256) {
        int k = e >> 7, c = e & 127;
        int tile = c >> 4, n = c & 15, s = k >> 5, q = (k >> 3) & 3, j = k & 7;
        int li = ((((tile << 1) + s) * 64) + (q << 4) + n) * 8 + j;
        lw2[li] = (__bf16)thW2[e];
        lg2[li] = (__bf16)thG2[e];
    }
    __syncthreads();

    int lane = tid & 63;
    int q = lane >> 4, n = lane & 15;
    int lfrag = ((q << 4) + n) << 3;
    int c2 = lane << 1;
    int wid = (blockIdx.x << 2) + (tid >> 6);
    int nw = gridDim.x << 2;

    for (int a = wid; a < NAT; a += nw) {
        // ---------- threebody atom ----------
        {
            int base = toff[a];
            int cnt = toff[a + 1] - base;
            floatx2 accT[8];
#pragma unroll
            for (int t = 0; t < 8; ++t) accT[t] = floatx2{0.f, 0.f};

            for (int i0 = 0; i0 < cnt; i0 += 64) {
                int rem = cnt - i0;
                float tx = 0.f, ty = 0.f, tz = 0.f;
                if (lane < rem) {
                    float2 p = tdata[base + i0 + lane];
                    unsigned bits = __float_as_uint(p.x);
                    tx = __half2float(__ushort_as_half((unsigned short)(bits & 0xffff)));
                    ty = __half2float(__ushort_as_half((unsigned short)(bits >> 16)));
                    tz = p.y;
                }
                float rrv[4], kkv[4], ccv[4];
#pragma unroll
                for (int ms = 0; ms < 4; ++ms) {
                    rrv[ms] = __shfl(tx, (ms << 4) + n);
                    kkv[ms] = __shfl(ty, (ms << 4) + n);
                    ccv[ms] = __shfl(tz, (ms << 4) + n);
                }
                int nms = rem >= 64 ? 4 : ((rem + 15) >> 4);

                bf16x8 fam[4][2], fag[4][2];
#pragma unroll
                for (int s = 0; s < 2; ++s) {
                    int kb = s * 32 + (q << 3);
#pragma unroll
                    for (int j2 = 0; j2 < 4; ++j2) {
                        floatx2 wa0 = *(const floatx2*)&lw1[kb + 2 * j2];
                        floatx2 wa1 = *(const floatx2*)&lw1[64 + kb + 2 * j2];
                        floatx2 wa2 = *(const floatx2*)&lw1[128 + kb + 2 * j2];
                        floatx2 wb0 = *(const floatx2*)&lg1[kb + 2 * j2];
                        floatx2 wb1 = *(const floatx2*)&lg1[64 + kb + 2 * j2];
                        floatx2 wb2 = *(const floatx2*)&lg1[128 + kb + 2 * j2];
#pragma unroll
                        for (int ms = 0; ms < 4; ++ms) {
                            if (ms >= nms) break;
                            floatx2 rr2 = {rrv[ms], rrv[ms]};
                            floatx2 kk2 = {kkv[ms], kkv[ms]};
                            floatx2 cc2 = {ccv[ms], ccv[ms]};
                            floatx2 um = rr2 * wa0 + kk2 * wa1 + cc2 * wa2;
                            floatx2 ug = rr2 * wb0 + kk2 * wb1 + cc2 * wb2;
                            floatx2 sm = fsilu2(um);
                            floatx2 sg = fsilu2(ug);
                            fam[ms][s][2 * j2]     = (__bf16)sm.x;
                            fam[ms][s][2 * j2 + 1] = (__bf16)sm.y;
                            fag[ms][s][2 * j2]     = (__bf16)sg.x;
                            fag[ms][s][2 * j2 + 1] = (__bf16)sg.y;
                        }
                    }
                }

#pragma unroll
                for (int tile = 0; tile < 8; ++tile) {
                    __builtin_amdgcn_sched_barrier(0);
                    const __bf16* pw = lw2 + lfrag + tile * 1024;
                    const __bf16* pg = lg2 + lfrag + tile * 1024;
                    bf16x8 bw0 = *(const bf16x8*)(pw);
                    bf16x8 bw1 = *(const bf16x8*)(pw + 512);
                    bf16x8 bg0 = *(const bf16x8*)(pg);
                    bf16x8 bg1 = *(const bf16x8*)(pg + 512);
#pragma unroll
                    for (int ms = 0; ms < 4; ++ms) {
                        if (ms >= nms) break;
                        floatx4 am = {0.f, 0.f, 0.f, 0.f};
                        floatx4 ag = {0.f, 0.f, 0.f, 0.f};
                        am = __builtin_amdgcn_mfma_f32_16x16x32_bf16(fam[ms][0], bw0, am, 0, 0, 0);
                        am = __builtin_amdgcn_mfma_f32_16x16x32_bf16(fam[ms][1], bw1, am, 0, 0, 0);
                        ag = __builtin_amdgcn_mfma_f32_16x16x32_bf16(fag[ms][0], bg0, ag, 0, 0, 0);
                        ag = __builtin_amdgcn_mfma_f32_16x16x32_bf16(fag[ms][1], bg1, ag, 0, 0, 0);
                        floatx2 s01 = fsigmoid2(floatx2{ag[0], ag[1]});
                        floatx2 s23 = fsigmoid2(floatx2{ag[2], ag[3]});
                        accT[tile] += floatx2{am[0], am[1]} * s01
                                    + floatx2{am[2], am[3]} * s23;
                    }
                }
            }
#pragma unroll
            for (int tile = 0; tile < 8; ++tile) {
                float v = accT[tile].x + accT[tile].y;
                v += __shfl_xor(v, 16);
                v += __shfl_xor(v, 32);
                if (q == 0) W3[(size_t)a * 128 + (tile << 4) + n] = v;
            }
        }
        // ---------- twobody atom (latency-bound; rides threebody stalls) ----------
        {
            int base = eoff[a];
            int cnt = eoff[a + 1] - base;
            float s0 = 0.f, s1 = 0.f, t0 = 0.f, t1 = 0.f;
            for (int i0 = 0; i0 < cnt; i0 += 64) {
                int rem = cnt - i0; if (rem > 64) rem = 64;
                float2 el = make_float2(0.f, 0.f);
                if (lane < rem) el = edata[base + i0 + lane];
                int j = 0;
                for (; j + 2 <= rem; j += 2) {
                    float dA = __shfl(el.x, j);
                    int aA = __float_as_int(__shfl(el.y, j));
                    float dB = __shfl(el.x, j + 1);
                    int aB = __float_as_int(__shfl(el.y, j + 1));
                    float xA = dA * ((float)NB / 5.0f);
                    int iA = (int)xA; if (iA > NB - 1) iA = NB - 1;
                    float fA = xA - (float)iA;
                    float xB = dB * ((float)NB / 5.0f);
                    int iB = (int)xB; if (iB > NB - 1) iB = NB - 1;
                    float fB = xB - (float)iB;
                    float2 l0A = *(const float2*)&lut[(size_t)iA * 128 + c2];
                    float2 l1A = *(const float2*)&lut[(size_t)(iA + 1) * 128 + c2];
                    float2 hvA = *(const float2*)&h[(size_t)aA * 128 + c2];
                    float2 l0B = *(const float2*)&lut[(size_t)iB * 128 + c2];
                    float2 l1B = *(const float2*)&lut[(size_t)(iB + 1) * 128 + c2];
                    float2 hvB = *(const float2*)&h[(size_t)aB * 128 + c2];
                    s0 += hvA.x * (l0A.x + (l1A.x - l0A.x) * fA);
                    s1 += hvA.y * (l0A.y + (l1A.y - l0A.y) * fA);
                    t0 += hvB.x * (l0B.x + (l1B.x - l0B.x) * fB);
                    t1 += hvB.y * (l0B.y + (l1B.y - l0B.y) * fB);
                }
                if (j < rem) {
                    float d = __shfl(el.x, j);
                    int a1 = __float_as_int(__shfl(el.y, j));
                    float x = d * ((float)NB / 5.0f);
                    int i = (int)x; if (i > NB - 1) i = NB - 1;
                    float f = x - (float)i;
                    float2 l0 = *(const float2*)&lut[(size_t)i * 128 + c2];
                    float2 l1 = *(const float2*)&lut[(size_t)(i + 1) * 128 + c2];
                    float2 hv = *(const float2*)&h[(size_t)a1 * 128 + c2];
                    s0 += hv.x * (l0.x + (l1.x - l0.x) * f);
                    s1 += hv.y * (l0.y + (l1.y - l0.y) * f);
                }
            }
            acc[(size_t)a * 128 + c2] = s0 + t0;
            acc[(size_t)a * 128 + c2 + 1] = s1 + t1;
        }
    }
}

// ---------------- inject three-body rows (after fused_bodies) ----------------
__global__ __launch_bounds__(256) void inject(const float* __restrict__ h,
                                              const float* __restrict__ W3,
                                              const int* __restrict__ nl,
                                              float* __restrict__ acc) {
    int g = blockIdx.x * 256 + threadIdx.x;
    int row = g >> 7, c = g & 127;
    float v = h[g] * W3[g];
    unsafeAtomicAdd(&acc[(size_t)nl[row] * 128 + c], v);
}

extern "C" void kernel_launch(void* const* d_in, const int* in_sizes, int n_in,
                              void* d_out, int out_size, void* d_ws, size_t ws_size,
                              hipStream_t stream) {
    const float* features = (const float*)d_in[0];
    const float* dist = (const float*)d_in[1];
    const float* ang = (const float*)d_in[2];
    const float* rij = (const float*)d_in[3];
    const float* rik = (const float*)d_in[4];
    const int* nl = (const int*)d_in[5];
    const int* tri = (const int*)d_in[6];
    const float* W_pre = (const float*)d_in[7];
    const float* tbW1 = (const float*)d_in[8];
    const float* tbW2 = (const float*)d_in[9];
    const float* tbG1 = (const float*)d_in[10];
    const float* tbG2 = (const float*)d_in[11];
    const float* thW1 = (const float*)d_in[12];
    const float* thW2 = (const float*)d_in[13];
    const float* thG1 = (const float*)d_in[14];
    const float* thG2 = (const float*)d_in[15];
    const float* W_post = (const float*)d_in[16];
    float* out = (float*)d_out;

    // workspace layout (~44 MB); acc aliases d_out
    float2* tdata = (float2*)d_ws;                       // NT * 8B = 16 MB
    float2* edata = tdata + NT;                          // NE * 8B = 5.1 MB
    float* h   = (float*)(edata + NE);                   // 10.24 MB
    float* W3  = h + (size_t)NAT * CH;                   // 10.24 MB
    float* lut = W3 + (size_t)NAT * CH;                  // 2.1 MB
    int* tcnt = (int*)(lut + (size_t)(NB + 1) * CH);
    int* ecnt = tcnt + NAT;
    int* toff = ecnt + NAT;                              // NAT+1
    int* eoff = toff + NAT + 1;                          // NAT+1
    int* tcur = eoff + NAT + 1;
    int* ecur = tcur + NAT;
    float* acc = out;

    hipMemsetAsync(tcnt, 0, (size_t)2 * NAT * sizeof(int), stream);

    hist_k<<<1024, 256, 0, stream>>>(tri, nl, tcnt, ecnt);
    scan20k<<<2, 1024, 0, stream>>>(tcnt, toff, tcur, ecnt, eoff, ecur);
    mid_k<<<G_SC + G_GEMM + G_LUT, 256, 0, stream>>>(
        tri, nl, rij, rik, ang, dist, tcur, ecur, tdata, edata,
        features, W_pre, h, tbW1, tbW2, tbG1, tbG2, lut);
    fused_bodies<<<1024, 256, 0, stream>>>(tdata, toff, edata, eoff, h, lut,
                                           thW1, thW2, thG1, thG2, W3, acc);
    inject<<<NAT * CH / 256, 256, 0, stream>>>(h, W3, nl, acc);
    gemm128<<<NAT / 32, 256, 0, stream>>>(acc, W_post, out);
}